// Round 2
// baseline (497.359 us; speedup 1.0000x reference)
//
#include <hip/hip_runtime.h>
#include <hip/hip_bf16.h>

#define T_TOKENS 32768
#define HIDDEN   2048
#define NEXP     128
#define TOPK     8
#define BT       32          // tokens per block
#define BH       32          // hidden chunk per LDS tile
#define LDW      34          // f64 LDS stride for tiles (34 doubles/row)
#define LGLD     129         // f64 LDS stride for logits

__global__ __launch_bounds__(256)
void router_kernel(const float* __restrict__ X,
                   const float* __restrict__ W,
                   float* __restrict__ out)
{
    // f64 tiles: Xs [32][34] + Ws [128][34] = 5440 doubles = 43.5 KB
    // union with f64 logits [32][129] = 4128 doubles
    __shared__ __align__(16) double smem[(BT + NEXP) * LDW];
    double* Xs = smem;
    double* Ws = smem + BT * LDW;
    double* lg = smem;

    const int tid = threadIdx.x;
    const int t0  = blockIdx.x * BT;
    const int tx  = tid & 15;   // experts tx + 16*j, j<8
    const int ty  = tid >> 4;   // tokens  ty + 16*i, i<2

    double acc[2][8];
    #pragma unroll
    for (int i = 0; i < 2; ++i)
        #pragma unroll
        for (int j = 0; j < 8; ++j) acc[i][j] = 0.0;

    for (int kt = 0; kt < HIDDEN / BH; ++kt) {
        // stage X tile (32x32): 256 float4 -> one per thread, cvt to f64
        {
            int r = tid >> 3, c = (tid & 7) << 2;
            float4 v = *(const float4*)(X + (size_t)(t0 + r) * HIDDEN + kt * BH + c);
            double* p = Xs + r * LDW + c;
            p[0] = (double)v.x; p[1] = (double)v.y; p[2] = (double)v.z; p[3] = (double)v.w;
        }
        // stage W tile (128x32): 1024 float4 -> four per thread
        #pragma unroll
        for (int q = 0; q < 4; ++q) {
            int i = tid + q * 256;
            int r = i >> 3, c = (i & 7) << 2;
            float4 v = *(const float4*)(W + (size_t)r * HIDDEN + kt * BH + c);
            double* p = Ws + r * LDW + c;
            p[0] = (double)v.x; p[1] = (double)v.y; p[2] = (double)v.z; p[3] = (double)v.w;
        }
        __syncthreads();

        #pragma unroll
        for (int h = 0; h < BH; h += 2) {
            double2 xv0 = *(const double2*)(Xs + ty * LDW + h);
            double2 xv1 = *(const double2*)(Xs + (ty + 16) * LDW + h);
            double2 wv[8];
            #pragma unroll
            for (int j = 0; j < 8; ++j)
                wv[j] = *(const double2*)(Ws + (tx + 16 * j) * LDW + h);
            #pragma unroll
            for (int j = 0; j < 8; ++j) {
                acc[0][j] = fma(xv0.x, wv[j].x, acc[0][j]);
                acc[0][j] = fma(xv0.y, wv[j].y, acc[0][j]);
                acc[1][j] = fma(xv1.x, wv[j].x, acc[1][j]);
                acc[1][j] = fma(xv1.y, wv[j].y, acc[1][j]);
            }
        }
        __syncthreads();
    }

    // f64 logits -> LDS (tiles dead after final barrier above)
    #pragma unroll
    for (int i = 0; i < 2; ++i)
        #pragma unroll
        for (int j = 0; j < 8; ++j)
            lg[(ty + 16 * i) * LGLD + (tx + 16 * j)] = acc[i][j];

    // cooperative coalesced zero of this block's dense score rows (32x128 f32)
    float* scoreBase = out + (size_t)t0 * NEXP;
    #pragma unroll
    for (int q = 0; q < 4; ++q) {
        int i = tid + q * 256;
        *(float4*)(scoreBase + i * 4) = make_float4(0.f, 0.f, 0.f, 0.f);
    }
    __syncthreads();

    // epilogue: one thread per token; top-8 selected on f64 LOGITS
    // (exp is monotone -> same order as probs; f64 ties ~never occur)
    if (tid < BT) {
        double* row = lg + tid * LGLD;

        int idx[TOPK]; double lval[TOPK];
        #pragma unroll
        for (int k = 0; k < TOPK; ++k) {
            double best = -1e300; int bi = 0;
            for (int e = 0; e < NEXP; ++e) {
                double v = row[e];
                if (v > best) { best = v; bi = e; }   // strict > : lower index wins ties
            }
            idx[k] = bi; lval[k] = best;
            row[bi] = -1e300;
        }

        // values: p_k = exp(l_k - m); renormalized val_k = p_k / sum(p) —
        // softmax denominator cancels, f32 precision is ample for 2% threshold
        float m = (float)lval[0];   // first pick is the max logit
        float p[TOPK]; float ksum = 0.f;
        #pragma unroll
        for (int k = 0; k < TOPK; ++k) {
            p[k] = expf((float)lval[k] - m);
            ksum += p[k];
        }

        const int tg = t0 + tid;
        float* srow = out + (size_t)tg * NEXP;
        float* irow = out + (size_t)T_TOKENS * NEXP + (size_t)tg * TOPK;
        #pragma unroll
        for (int k = 0; k < TOPK; ++k) {
            srow[idx[k]] = p[k] / ksum;
            irow[k] = (float)idx[k];
        }
    }
}

extern "C" void kernel_launch(void* const* d_in, const int* in_sizes, int n_in,
                              void* d_out, int out_size, void* d_ws, size_t ws_size,
                              hipStream_t stream) {
    const float* X = (const float*)d_in[0];
    const float* W = (const float*)d_in[1];
    float* out = (float*)d_out;
    dim3 grid(T_TOKENS / BT), block(256);
    router_kernel<<<grid, block, 0, stream>>>(X, W, out);
}

// Round 3
// 378.853 us; speedup vs baseline: 1.3128x; 1.3128x over previous
//
#include <hip/hip_runtime.h>
#include <hip/hip_bf16.h>

#define NT   32768
#define NH   2048
#define NE   128
#define TOPK 8
#define BT   64
#define BK   64
#define KT   (NH / BK)       // 32
#define BND    6.0e-4f       // per-logit worst-case error bound B (see header math)
#define TWO_B  (2.0f * BND)

// ws layout (bytes):
//   [0,64):        u32 flagged-token counter (memset 0 each launch)
//   [64, +512KB):  W0 bf16 [128][2048]
//   [+512KB, +1MB):W1 bf16 [128][2048]
//   [64+1MB, ...): records, 32B each, capacity 32768:
//                  u32 token, u32 cnt (0xFF => all-128), 16x u8 candidate ids
#define WS_REC_U32 262160      // (64 + 2*NE*NH*2 + 0)/4 = 1048640/4

typedef __attribute__((ext_vector_type(8))) short bf16x8;
typedef __attribute__((ext_vector_type(4))) float f32x4;

static __device__ __forceinline__ unsigned short f2bf(float f) {
    __hip_bfloat16 h = __float2bfloat16(f);
    return *reinterpret_cast<unsigned short*>(&h);
}
static __device__ __forceinline__ float bf2f(unsigned short u) {
    __hip_bfloat16 h;
    *reinterpret_cast<unsigned short*>(&h) = u;
    return __bfloat162float(h);
}

// ---------------- K0: split router weight into 2x bf16 ----------------
__global__ __launch_bounds__(256) void splitW_kernel(
    const float* __restrict__ W, unsigned short* __restrict__ W0,
    unsigned short* __restrict__ W1)
{
    int i = blockIdx.x * 256 + threadIdx.x;           // 65536 float4s
    float4 v = *(const float4*)(W + (size_t)i * 4);
    float f[4] = {v.x, v.y, v.z, v.w};
    unsigned int a0 = 0, b0 = 0, a1 = 0, b1 = 0;
    {
        unsigned short h0 = f2bf(f[0]); unsigned short h1 = f2bf(f[1]);
        unsigned short h2 = f2bf(f[2]); unsigned short h3 = f2bf(f[3]);
        a0 = (unsigned int)h0 | ((unsigned int)h1 << 16);
        b0 = (unsigned int)h2 | ((unsigned int)h3 << 16);
        unsigned short l0 = f2bf(f[0] - bf2f(h0));
        unsigned short l1 = f2bf(f[1] - bf2f(h1));
        unsigned short l2 = f2bf(f[2] - bf2f(h2));
        unsigned short l3 = f2bf(f[3] - bf2f(h3));
        a1 = (unsigned int)l0 | ((unsigned int)l1 << 16);
        b1 = (unsigned int)l2 | ((unsigned int)l3 << 16);
    }
    *(uint2*)(W0 + (size_t)i * 4) = make_uint2(a0, b0);
    *(uint2*)(W1 + (size_t)i * 4) = make_uint2(a1, b1);
}

// ---------------- K1: split-bf16 MFMA GEMM + select + flag ----------------
__global__ __launch_bounds__(256) void router_gemm_kernel(
    const float* __restrict__ X, const unsigned short* __restrict__ W0,
    const unsigned short* __restrict__ W1, float* __restrict__ out,
    unsigned int* __restrict__ ws)
{
    // LDS: Xs[2][64][64]bf16 swizzled (16KB) + Ws[2][128][64]bf16 swizzled (32KB)
    // union with f32 logits [64][129] (33KB) after GEMM. Total 48KB -> 3 blocks/CU.
    __shared__ __align__(16) char smem[49152];

    const int tid  = threadIdx.x;
    const int t0   = blockIdx.x * BT;
    const int lane = tid & 63;
    const int wid  = tid >> 6;
    const int wr   = wid >> 1, wc = wid & 1;   // wave tile: 32 tok x 64 exp
    const int l15  = lane & 15, lhi = lane >> 4;

    f32x4 acc[2][4];
    #pragma unroll
    for (int i = 0; i < 2; ++i)
        #pragma unroll
        for (int j = 0; j < 4; ++j)
            acc[i][j] = (f32x4){0.f, 0.f, 0.f, 0.f};

    for (int kt = 0; kt < KT; ++kt) {
        const int k0 = kt * BK;
        // ---- stage X (f32 -> 2x bf16 split, XOR-swizzled 16B slots) ----
        #pragma unroll
        for (int q = 0; q < 4; ++q) {
            int i = tid + q * 256;
            int r = i >> 4, c4 = i & 15;            // row 0..63, float4 col 0..15
            float4 v = *(const float4*)(X + (size_t)(t0 + r) * NH + k0 + c4 * 4);
            float f[4] = {v.x, v.y, v.z, v.w};
            unsigned short h0 = f2bf(f[0]), h1 = f2bf(f[1]), h2 = f2bf(f[2]), h3 = f2bf(f[3]);
            unsigned int p0 = (unsigned int)h0 | ((unsigned int)h1 << 16);
            unsigned int p1 = (unsigned int)h2 | ((unsigned int)h3 << 16);
            unsigned short g0 = f2bf(f[0] - bf2f(h0)), g1 = f2bf(f[1] - bf2f(h1));
            unsigned short g2 = f2bf(f[2] - bf2f(h2)), g3 = f2bf(f[3] - bf2f(h3));
            unsigned int q0 = (unsigned int)g0 | ((unsigned int)g1 << 16);
            unsigned int q1 = (unsigned int)g2 | ((unsigned int)g3 << 16);
            int slot = (c4 >> 1) ^ (r & 7);
            char* d0 = smem + r * 128 + slot * 16 + (c4 & 1) * 8;
            *(uint2*)d0          = make_uint2(p0, p1);
            *(uint2*)(d0 + 8192) = make_uint2(q0, q1);
        }
        // ---- stage W splits (bf16 from ws, XOR-swizzled) ----
        #pragma unroll
        for (int s = 0; s < 2; ++s) {
            const unsigned short* Wsrc = s ? W1 : W0;
            #pragma unroll
            for (int q = 0; q < 4; ++q) {
                int i = tid + q * 256;
                int r = i >> 3, c8 = i & 7;        // row 0..127, 16B chunk 0..7
                uint4 v = *(const uint4*)(Wsrc + (size_t)r * NH + k0 + c8 * 8);
                int slot = c8 ^ (r & 7);
                *(uint4*)(smem + 16384 + s * 16384 + r * 128 + slot * 16) = v;
            }
        }
        __syncthreads();
        // ---- MFMA: 2 K-chunks x (2 tok-tiles x 4 exp-tiles x 4 split-combos) ----
        #pragma unroll
        for (int kk = 0; kk < 2; ++kk) {
            bf16x8 af[2][2], bfr[4][2];
            #pragma unroll
            for (int i = 0; i < 2; ++i)
                #pragma unroll
                for (int s = 0; s < 2; ++s) {
                    int row  = wr * 32 + i * 16 + l15;
                    int slot = (kk * 4 + lhi) ^ (row & 7);
                    af[i][s] = *(const bf16x8*)(smem + s * 8192 + row * 128 + slot * 16);
                }
            #pragma unroll
            for (int j = 0; j < 4; ++j)
                #pragma unroll
                for (int s = 0; s < 2; ++s) {
                    int row  = wc * 64 + j * 16 + l15;
                    int slot = (kk * 4 + lhi) ^ (row & 7);
                    bfr[j][s] = *(const bf16x8*)(smem + 16384 + s * 16384 + row * 128 + slot * 16);
                }
            #pragma unroll
            for (int i = 0; i < 2; ++i)
                #pragma unroll
                for (int j = 0; j < 4; ++j) {
                    acc[i][j] = __builtin_amdgcn_mfma_f32_16x16x32_bf16(af[i][0], bfr[j][0], acc[i][j], 0, 0, 0);
                    acc[i][j] = __builtin_amdgcn_mfma_f32_16x16x32_bf16(af[i][0], bfr[j][1], acc[i][j], 0, 0, 0);
                    acc[i][j] = __builtin_amdgcn_mfma_f32_16x16x32_bf16(af[i][1], bfr[j][0], acc[i][j], 0, 0, 0);
                    acc[i][j] = __builtin_amdgcn_mfma_f32_16x16x32_bf16(af[i][1], bfr[j][1], acc[i][j], 0, 0, 0);
                }
        }
        __syncthreads();
    }

    // ---- logits -> LDS (f32, stride 129; GEMM tiles dead) ----
    float* lg = (float*)smem;
    #pragma unroll
    for (int i = 0; i < 2; ++i)
        #pragma unroll
        for (int j = 0; j < 4; ++j)
            #pragma unroll
            for (int q = 0; q < 4; ++q) {
                int tr = wr * 32 + i * 16 + lhi * 4 + q;   // C/D: row=(lane>>4)*4+reg
                int ec = wc * 64 + j * 16 + l15;           //      col=lane&15
                lg[tr * 129 + ec] = acc[i][j][q];
            }

    // ---- cooperative zero of this block's dense score rows ----
    float* scoreBase = out + (size_t)t0 * NE;
    #pragma unroll
    for (int q = 0; q < 8; ++q) {
        int i = tid + q * 256;
        *(float4*)(scoreBase + (size_t)i * 4) = make_float4(0.f, 0.f, 0.f, 0.f);
    }
    __syncthreads();

    // ---- per-token epilogue: top-13 insert-sort, gap check, flag ----
    if (tid < BT) {
        const float* row = lg + tid * 129;
        float tv[13]; int ti[13];
        #pragma unroll
        for (int k = 0; k < 13; ++k) { tv[k] = -3.0e38f; ti[k] = 0; }
        for (int e = 0; e < NE; ++e) {
            float v = row[e];
            if (v > tv[12]) {
                float cv = v; int ci = e;
                #pragma unroll
                for (int s = 0; s < 13; ++s) {
                    if (cv > tv[s]) {
                        float t1 = tv[s]; int t2 = ti[s];
                        tv[s] = cv; ti[s] = ci; cv = t1; ci = t2;
                    }
                }
            }
        }
        bool flag = false;
        #pragma unroll
        for (int k = 0; k < 8; ++k) flag |= (tv[k] - tv[k + 1] < TWO_B);

        // provisional outputs (exact for unflagged tokens; K2 overwrites flagged)
        float pv[8]; float ksum = 0.f;
        #pragma unroll
        for (int k = 0; k < 8; ++k) { pv[k] = expf(tv[k] - tv[0]); ksum += pv[k]; }
        const int tg = t0 + tid;
        float* srow = out + (size_t)tg * NE;
        float* irow = out + (size_t)NT * NE + (size_t)tg * TOPK;
        #pragma unroll
        for (int k = 0; k < 8; ++k) {
            srow[ti[k]] = pv[k] / ksum;
            irow[k] = (float)ti[k];
        }

        if (flag) {
            unsigned int cnt;
            unsigned int idw[4] = {0u, 0u, 0u, 0u};
            float thr = tv[7] - TWO_B;
            if (tv[12] >= thr) {
                cnt = 0xFFu;               // can't bound candidate set -> full recompute
            } else {
                cnt = 0;
                #pragma unroll
                for (int k = 0; k < 13; ++k) {
                    if (k < 8 || tv[k] >= thr) {
                        idw[cnt >> 2] |= ((unsigned int)ti[k]) << ((cnt & 3) * 8);
                        ++cnt;
                    }
                }
            }
            unsigned int slot = atomicAdd(ws, 1u);
            unsigned int* rec = ws + WS_REC_U32 + slot * 8;
            rec[0] = (unsigned int)tg;
            rec[1] = cnt;
            rec[2] = idw[0]; rec[3] = idw[1]; rec[4] = idw[2]; rec[5] = idw[3];
        }
    }
}

// ---------------- K2: f64 refine flagged tokens ----------------
__global__ __launch_bounds__(256) void finalize_kernel(
    const float* __restrict__ X, const float* __restrict__ W,
    float* __restrict__ out, const unsigned int* __restrict__ ws)
{
    __shared__ float  xs[2048];
    __shared__ double cv[128];
    __shared__ int    cid[128];
    __shared__ float  ovals[8];
    __shared__ int    oidx[8];

    const int tid = threadIdx.x;
    const int lane = tid & 63, w = tid >> 6;
    const unsigned int n = ws[0];

    for (unsigned int rI = blockIdx.x; rI < n; rI += gridDim.x) {
        const unsigned int* rec = ws + WS_REC_U32 + rI * 8;
        const int tg = (int)rec[0];
        const unsigned int cnt = rec[1];
        const unsigned char* ids = (const unsigned char*)(rec + 2);
        const int nc = (cnt == 0xFFu) ? NE : (int)cnt;

        #pragma unroll
        for (int q = 0; q < 2; ++q) {
            int i = tid + q * 256;
            *(float4*)(xs + i * 4) = *(const float4*)(X + (size_t)tg * NH + i * 4);
        }
        __syncthreads();

        for (int c = w; c < nc; c += 4) {
            int e = (cnt == 0xFFu) ? c : (int)ids[c];
            const float* wrow = W + (size_t)e * NH;
            double s = 0.0;
            #pragma unroll
            for (int m = 0; m < 8; ++m) {
                float4 wv = *(const float4*)(wrow + m * 256 + lane * 4);
                float4 xv = *(const float4*)(xs + m * 256 + lane * 4);
                s = fma((double)xv.x, (double)wv.x, s);
                s = fma((double)xv.y, (double)wv.y, s);
                s = fma((double)xv.z, (double)wv.z, s);
                s = fma((double)xv.w, (double)wv.w, s);
            }
            #pragma unroll
            for (int off = 32; off >= 1; off >>= 1) s += __shfl_xor(s, off);
            if (lane == 0) { cv[c] = s; cid[c] = e; }
        }
        __syncthreads();

        if (tid == 0) {
            double lv[8];
            #pragma unroll
            for (int k = 0; k < 8; ++k) {
                double best = -1.0e300; int bi = 1 << 30, bc = 0;
                for (int c = 0; c < nc; ++c) {
                    double v = cv[c]; int e = cid[c];
                    if (v > best || (v == best && e < bi)) { best = v; bi = e; bc = c; }
                }
                lv[k] = best; oidx[k] = bi; cv[bc] = -1.0e301;
            }
            double m = lv[0], sum = 0.0, p[8];
            #pragma unroll
            for (int k = 0; k < 8; ++k) { p[k] = exp(lv[k] - m); sum += p[k]; }
            #pragma unroll
            for (int k = 0; k < 8; ++k) ovals[k] = (float)(p[k] / sum);
        }
        __syncthreads();

        float* srow = out + (size_t)tg * NE;
        if (tid < NE) {
            float val = 0.f;
            #pragma unroll
            for (int k = 0; k < 8; ++k) if (oidx[k] == tid) val = ovals[k];
            srow[tid] = val;
        }
        if (tid < TOPK) out[(size_t)NT * NE + (size_t)tg * TOPK + tid] = (float)oidx[tid];
        __syncthreads();
    }
}

extern "C" void kernel_launch(void* const* d_in, const int* in_sizes, int n_in,
                              void* d_out, int out_size, void* d_ws, size_t ws_size,
                              hipStream_t stream) {
    const float* X = (const float*)d_in[0];
    const float* W = (const float*)d_in[1];
    float* out = (float*)d_out;
    unsigned char* wsb = (unsigned char*)d_ws;
    unsigned short* W0 = (unsigned short*)(wsb + 64);
    unsigned short* W1 = (unsigned short*)(wsb + 64 + (size_t)NE * NH * 2);

    hipMemsetAsync(d_ws, 0, 64, stream);                       // flagged counter
    splitW_kernel<<<256, 256, 0, stream>>>(W, W0, W1);
    router_gemm_kernel<<<NT / BT, 256, 0, stream>>>(X, W0, W1, out, (unsigned int*)d_ws);
    finalize_kernel<<<1024, 256, 0, stream>>>(X, W, out, (const unsigned int*)d_ws);
}

// Round 4
// 232.184 us; speedup vs baseline: 2.1421x; 1.6317x over previous
//
#include <hip/hip_runtime.h>
#include <hip/hip_bf16.h>

#define NT   32768
#define NH   2048
#define NE   128
#define TOPK 8
#define BT   64
#define BK   32
#define NKT  (NH / BK)       // 64 K-steps
#define BND    6.0e-4f
#define TWO_B  (2.0f * BND)

// ws layout (bytes):
//   [0,64):          u32 flagged-token counter
//   [64, 64+1MB):    W tiles, pre-swizzled bf16 hi/lo in gload_lds deposit order
//                    tile t (16KB): chunk g16 = i*64+l holds split s of
//                    W[8i+(l>>3)][t*32 + (u&3)*8 ..+8), u = (l&7)^(l>>3), s=u>>2
//   [64+1MB, ...):   records, 32B each: u32 token, u32 cnt, 16x u8 cand ids
#define WS_W_OFF   64
#define WS_REC_U32 262160     // (64 + 1MB)/4

typedef __attribute__((ext_vector_type(8))) short bf16x8;
typedef __attribute__((ext_vector_type(4))) float f32x4;

static __device__ __forceinline__ unsigned short f2bf(float f) {
    __hip_bfloat16 h = __float2bfloat16(f);
    return *reinterpret_cast<unsigned short*>(&h);
}

typedef __attribute__((address_space(3))) unsigned int lds_uint;
typedef const __attribute__((address_space(1))) unsigned int glb_uint;
static __device__ __forceinline__ void gld16(const void* g, void* l) {
    __builtin_amdgcn_global_load_lds((glb_uint*)g, (lds_uint*)l, 16, 0, 0);
}

// ---------------- K0: build pre-swizzled W hi/lo tiles in ws ----------------
__global__ __launch_bounds__(256) void prep_w_kernel(
    const float* __restrict__ W, unsigned short* __restrict__ Wt)
{
    int g = blockIdx.x * 256 + threadIdx.x;   // 65536 16B-chunks (1 MB)
    int t = g >> 10;                          // k-step tile 0..63
    int m = g & 1023;
    int i = m >> 6;                           // issue 0..15
    int l = m & 63;                           // lane
    int r = 8 * i + (l >> 3);                 // expert row 0..127
    int u = (l & 7) ^ (l >> 3);               // original 16B slot
    int s = u >> 2;                           // split (0=hi,1=lo)
    int koff = (u & 3) * 8;
    const float* src = W + (size_t)r * NH + t * BK + koff;
    float4 f0 = *(const float4*)src;
    float4 f1 = *(const float4*)(src + 4);
    float f[8] = {f0.x, f0.y, f0.z, f0.w, f1.x, f1.y, f1.z, f1.w};
    bf16x8 o;
    #pragma unroll
    for (int e = 0; e < 8; ++e) {
        unsigned short h = f2bf(f[e]);
        if (s == 0) o[e] = (short)h;
        else {
            float fh = __builtin_bit_cast(float, ((unsigned int)h) << 16);
            o[e] = (short)f2bf(f[e] - fh);
        }
    }
    *(bf16x8*)(Wt + (size_t)g * 8) = o;
}

// ---------------- K1: gload_lds double-buffered split-bf16 MFMA GEMM ----------------
__global__ __launch_bounds__(256, 2) void router_gemm_kernel(
    const float* __restrict__ X, const unsigned short* __restrict__ Wt,
    float* __restrict__ out, unsigned int* __restrict__ ws)
{
    // per buffer: X f32 [64][8 slots x16B] = 8KB, W bf16 [128][8 slots] = 16KB
    __shared__ __align__(16) char smem[49152];

    const int tid  = threadIdx.x;
    const int t0   = blockIdx.x * BT;
    const int lane = tid & 63;
    const int wid  = tid >> 6;
    const int wr   = wid >> 1, wc = wid & 1;   // wave tile: 32 tok x 64 exp
    const int l15  = lane & 15, lhi = lane >> 4;
    const int l8   = lane >> 3, l7 = lane & 7;
    const int xu   = l7 ^ l8;                  // X-source slot pre-swizzle

    const char* Xg = (const char*)X;
    const char* Wg = (const char*)Wt;

    f32x4 acc[2][4];
    #pragma unroll
    for (int i = 0; i < 2; ++i)
        #pragma unroll
        for (int j = 0; j < 4; ++j) acc[i][j] = (f32x4){0.f, 0.f, 0.f, 0.f};

    #define STAGE(KT, B) do {                                                   \
        char* Xb_ = smem + (B) * 24576;                                         \
        char* Wb_ = Xb_ + 8192;                                                 \
        _Pragma("unroll")                                                       \
        for (int q = 0; q < 2; ++q) {                                           \
            int i_ = wid * 2 + q;                                               \
            const char* s_ = Xg + (size_t)(t0 + 8 * i_ + l8) * 8192             \
                             + (size_t)(KT) * 128 + xu * 16;                    \
            gld16(s_, Xb_ + i_ * 1024);                                         \
        }                                                                       \
        _Pragma("unroll")                                                       \
        for (int q = 0; q < 4; ++q) {                                           \
            int i_ = wid * 4 + q;                                               \
            const char* s_ = Wg + (size_t)(KT) * 16384 + i_ * 1024 + lane * 16; \
            gld16(s_, Wb_ + i_ * 1024);                                         \
        }                                                                       \
    } while (0)

    STAGE(0, 0);
    __syncthreads();

    for (int kt = 0; kt < NKT; ++kt) {
        const int cur = kt & 1;
        if (kt + 1 < NKT) STAGE(kt + 1, cur ^ 1);

        const char* Xb = smem + cur * 24576;
        const char* Wb = Xb + 8192;

        bf16x8 ah[2], al[2];
        #pragma unroll
        for (int i = 0; i < 2; ++i) {
            int ar = wr * 32 + i * 16 + l15;
            int r7 = ar & 7;
            const char* rp = Xb + ar * 128;
            float4 fa = *(const float4*)(rp + (((2 * lhi) ^ r7) * 16));
            float4 fb = *(const float4*)(rp + (((2 * lhi + 1) ^ r7) * 16));
            float f[8] = {fa.x, fa.y, fa.z, fa.w, fb.x, fb.y, fb.z, fb.w};
            #pragma unroll
            for (int e = 0; e < 8; ++e) {
                unsigned short h = f2bf(f[e]);
                ah[i][e] = (short)h;
                float fh = __builtin_bit_cast(float, ((unsigned int)h) << 16);
                al[i][e] = (short)f2bf(f[e] - fh);
            }
        }
        bf16x8 bw[4][2];
        #pragma unroll
        for (int j = 0; j < 4; ++j) {
            int br = wc * 64 + j * 16 + l15;
            int r7 = br & 7;
            const char* rp = Wb + br * 128;
            bw[j][0] = *(const bf16x8*)(rp + ((lhi ^ r7) * 16));        // hi: u=lhi
            bw[j][1] = *(const bf16x8*)(rp + (((4 + lhi) ^ r7) * 16));  // lo: u=4+lhi
        }
        #pragma unroll
        for (int i = 0; i < 2; ++i)
            #pragma unroll
            for (int j = 0; j < 4; ++j) {
                acc[i][j] = __builtin_amdgcn_mfma_f32_16x16x32_bf16(ah[i], bw[j][0], acc[i][j], 0, 0, 0);
                acc[i][j] = __builtin_amdgcn_mfma_f32_16x16x32_bf16(al[i], bw[j][0], acc[i][j], 0, 0, 0);
                acc[i][j] = __builtin_amdgcn_mfma_f32_16x16x32_bf16(ah[i], bw[j][1], acc[i][j], 0, 0, 0);
            }
        __syncthreads();
    }

    // ---- logits -> LDS union (f32, stride 129) ----
    float* lg = (float*)smem;
    #pragma unroll
    for (int i = 0; i < 2; ++i)
        #pragma unroll
        for (int j = 0; j < 4; ++j)
            #pragma unroll
            for (int q = 0; q < 4; ++q) {
                int tr = wr * 32 + i * 16 + lhi * 4 + q;   // C/D: row=(lane>>4)*4+reg
                int ec = wc * 64 + j * 16 + l15;           //      col=lane&15
                lg[tr * 129 + ec] = acc[i][j][q];
            }

    // ---- cooperative zero of this block's dense score rows ----
    float* scoreBase = out + (size_t)t0 * NE;
    #pragma unroll
    for (int q = 0; q < 8; ++q) {
        int i = tid + q * 256;
        *(float4*)(scoreBase + (size_t)i * 4) = make_float4(0.f, 0.f, 0.f, 0.f);
    }
    __syncthreads();

    // ---- per-token epilogue: top-13 insert-sort, gap check, flag ----
    if (tid < BT) {
        const float* row = lg + tid * 129;
        float tv[13]; int ti[13];
        #pragma unroll
        for (int k = 0; k < 13; ++k) { tv[k] = -3.0e38f; ti[k] = 0; }
        for (int e = 0; e < NE; ++e) {
            float v = row[e];
            if (v > tv[12]) {
                float cv = v; int ci = e;
                #pragma unroll
                for (int s = 0; s < 13; ++s) {
                    if (cv > tv[s]) {
                        float t1 = tv[s]; int t2 = ti[s];
                        tv[s] = cv; ti[s] = ci; cv = t1; ci = t2;
                    }
                }
            }
        }
        bool flag = false;
        #pragma unroll
        for (int k = 0; k < 8; ++k) flag |= (tv[k] - tv[k + 1] < TWO_B);

        float pv[8]; float ksum = 0.f;
        #pragma unroll
        for (int k = 0; k < 8; ++k) { pv[k] = expf(tv[k] - tv[0]); ksum += pv[k]; }
        const int tg = t0 + tid;
        float* srow = out + (size_t)tg * NE;
        float* irow = out + (size_t)NT * NE + (size_t)tg * TOPK;
        #pragma unroll
        for (int k = 0; k < 8; ++k) {
            srow[ti[k]] = pv[k] / ksum;
            irow[k] = (float)ti[k];
        }

        if (flag) {
            unsigned int cnt;
            unsigned int idw[4] = {0u, 0u, 0u, 0u};
            float thr = tv[7] - TWO_B;
            if (tv[12] >= thr) {
                cnt = 0xFFu;
            } else {
                cnt = 0;
                #pragma unroll
                for (int k = 0; k < 13; ++k) {
                    if (k < 8 || tv[k] >= thr) {
                        idw[cnt >> 2] |= ((unsigned int)ti[k]) << ((cnt & 3) * 8);
                        ++cnt;
                    }
                }
            }
            unsigned int slot = atomicAdd(ws, 1u);
            unsigned int* rec = ws + WS_REC_U32 + slot * 8;
            rec[0] = (unsigned int)tg;
            rec[1] = cnt;
            rec[2] = idw[0]; rec[3] = idw[1]; rec[4] = idw[2]; rec[5] = idw[3];
        }
    }
}

// ---------------- K2: f64 refine flagged tokens ----------------
__global__ __launch_bounds__(256) void finalize_kernel(
    const float* __restrict__ X, const float* __restrict__ W,
    float* __restrict__ out, const unsigned int* __restrict__ ws)
{
    __shared__ float  xs[2048];
    __shared__ double cv[128];
    __shared__ int    cid[128];
    __shared__ float  ovals[8];
    __shared__ int    oidx[8];

    const int tid = threadIdx.x;
    const int lane = tid & 63, w = tid >> 6;
    const unsigned int n = ws[0];

    for (unsigned int rI = blockIdx.x; rI < n; rI += gridDim.x) {
        const unsigned int* rec = ws + WS_REC_U32 + rI * 8;
        const int tg = (int)rec[0];
        const unsigned int cnt = rec[1];
        const unsigned char* ids = (const unsigned char*)(rec + 2);
        const int nc = (cnt == 0xFFu) ? NE : (int)cnt;

        #pragma unroll
        for (int q = 0; q < 2; ++q) {
            int i = tid + q * 256;
            *(float4*)(xs + i * 4) = *(const float4*)(X + (size_t)tg * NH + i * 4);
        }
        __syncthreads();

        for (int c = w; c < nc; c += 4) {
            int e = (cnt == 0xFFu) ? c : (int)ids[c];
            const float* wrow = W + (size_t)e * NH;
            double s = 0.0;
            #pragma unroll
            for (int m = 0; m < 8; ++m) {
                float4 wv = *(const float4*)(wrow + m * 256 + lane * 4);
                float4 xv = *(const float4*)(xs + m * 256 + lane * 4);
                s = fma((double)xv.x, (double)wv.x, s);
                s = fma((double)xv.y, (double)wv.y, s);
                s = fma((double)xv.z, (double)wv.z, s);
                s = fma((double)xv.w, (double)wv.w, s);
            }
            #pragma unroll
            for (int off = 32; off >= 1; off >>= 1) s += __shfl_xor(s, off);
            if (lane == 0) { cv[c] = s; cid[c] = e; }
        }
        __syncthreads();

        if (tid == 0) {
            double lv[8];
            #pragma unroll
            for (int k = 0; k < 8; ++k) {
                double best = -1.0e300; int bi = 1 << 30, bc = 0;
                for (int c = 0; c < nc; ++c) {
                    double v = cv[c]; int e = cid[c];
                    if (v > best || (v == best && e < bi)) { best = v; bi = e; bc = c; }
                }
                lv[k] = best; oidx[k] = bi; cv[bc] = -1.0e301;
            }
            double m = lv[0], sum = 0.0, p[8];
            #pragma unroll
            for (int k = 0; k < 8; ++k) { p[k] = exp(lv[k] - m); sum += p[k]; }
            #pragma unroll
            for (int k = 0; k < 8; ++k) ovals[k] = (float)(p[k] / sum);
        }
        __syncthreads();

        float* srow = out + (size_t)tg * NE;
        if (tid < NE) {
            float val = 0.f;
            #pragma unroll
            for (int k = 0; k < 8; ++k) if (oidx[k] == tid) val = ovals[k];
            srow[tid] = val;
        }
        if (tid < TOPK) out[(size_t)NT * NE + (size_t)tg * TOPK + tid] = (float)oidx[tid];
        __syncthreads();
    }
}

extern "C" void kernel_launch(void* const* d_in, const int* in_sizes, int n_in,
                              void* d_out, int out_size, void* d_ws, size_t ws_size,
                              hipStream_t stream) {
    const float* X = (const float*)d_in[0];
    const float* W = (const float*)d_in[1];
    float* out = (float*)d_out;
    unsigned char* wsb = (unsigned char*)d_ws;
    unsigned short* Wt = (unsigned short*)(wsb + WS_W_OFF);

    hipMemsetAsync(d_ws, 0, 64, stream);
    prep_w_kernel<<<256, 256, 0, stream>>>(W, Wt);
    router_gemm_kernel<<<NT / BT, 256, 0, stream>>>(X, Wt, out, (unsigned int*)d_ws);
    finalize_kernel<<<1024, 256, 0, stream>>>(X, W, out, (const unsigned int*)d_ws);
}

// Round 5
// 230.319 us; speedup vs baseline: 2.1594x; 1.0081x over previous
//
#include <hip/hip_runtime.h>
#include <hip/hip_bf16.h>

#define NT   32768
#define NH   2048
#define NE   128
#define TOPK 8
#define BT   64
#define BK   32
#define NKT  (NH / BK)       // 64 K-steps
#define BUFB 24576           // bytes per LDS buffer (X 8KB + W 16KB)
#define BND    6.0e-4f
#define TWO_B  (2.0f * BND)

// ws layout (bytes):
//   [0,64):          u32 flagged-token counter
//   [64, 64+1MB):    W tiles, pre-swizzled bf16 hi/lo in gload_lds deposit order
//   [64+1MB, ...):   records, 32B each: u32 token, u32 cnt, 16x u8 cand ids
#define WS_W_OFF   64
#define WS_REC_U32 262160     // (64 + 1MB)/4

typedef __attribute__((ext_vector_type(8))) short bf16x8;
typedef __attribute__((ext_vector_type(4))) float f32x4;

static __device__ __forceinline__ unsigned short f2bf(float f) {
    __hip_bfloat16 h = __float2bfloat16(f);
    return *reinterpret_cast<unsigned short*>(&h);
}

typedef __attribute__((address_space(3))) unsigned int lds_uint;
typedef const __attribute__((address_space(1))) unsigned int glb_uint;
static __device__ __forceinline__ void gld16(const void* g, void* l) {
    __builtin_amdgcn_global_load_lds((glb_uint*)g, (lds_uint*)l, 16, 0, 0);
}

// ---------------- K0: build pre-swizzled W hi/lo tiles in ws ----------------
__global__ __launch_bounds__(256) void prep_w_kernel(
    const float* __restrict__ W, unsigned short* __restrict__ Wt)
{
    int g = blockIdx.x * 256 + threadIdx.x;   // 65536 16B-chunks (1 MB)
    int t = g >> 10;                          // k-step tile 0..63
    int m = g & 1023;
    int i = m >> 6;                           // issue 0..15
    int l = m & 63;                           // lane
    int r = 8 * i + (l >> 3);                 // expert row 0..127
    int u = (l & 7) ^ (l >> 3);               // original 16B slot
    int s = u >> 2;                           // split (0=hi,1=lo)
    int koff = (u & 3) * 8;
    const float* src = W + (size_t)r * NH + t * BK + koff;
    float4 f0 = *(const float4*)src;
    float4 f1 = *(const float4*)(src + 4);
    float f[8] = {f0.x, f0.y, f0.z, f0.w, f1.x, f1.y, f1.z, f1.w};
    bf16x8 o;
    #pragma unroll
    for (int e = 0; e < 8; ++e) {
        unsigned short h = f2bf(f[e]);
        if (s == 0) o[e] = (short)h;
        else {
            float fh = __builtin_bit_cast(float, ((unsigned int)h) << 16);
            o[e] = (short)f2bf(f[e] - fh);
        }
    }
    *(bf16x8*)(Wt + (size_t)g * 8) = o;
}

// ---------------- K1: depth-2 pipelined split-bf16 MFMA GEMM ----------------
__global__ __launch_bounds__(512, 4) void router_gemm_kernel(
    const float* __restrict__ X, const unsigned short* __restrict__ Wt,
    float* __restrict__ out, unsigned int* __restrict__ ws)
{
    // 3 buffers x 24KB = 72KB; union with f32 logits [64][129] after GEMM.
    __shared__ __align__(16) char smem[73728];

    const int tid  = threadIdx.x;
    const int t0   = blockIdx.x * BT;
    const int lane = tid & 63;
    const int wid  = tid >> 6;                 // 0..7
    const int wr   = wid >> 1, wc = wid & 1;   // wave tile: 16 tok x 64 exp
    const int l15  = lane & 15, lhi = lane >> 4;
    const int l8   = lane >> 3, l7 = lane & 7;
    const int xu   = l7 ^ l8;                  // X-source slot pre-swizzle

    const char* Xg = (const char*)X;
    const char* Wg = (const char*)Wt;

    f32x4 acc[4];
    #pragma unroll
    for (int j = 0; j < 4; ++j) acc[j] = (f32x4){0.f, 0.f, 0.f, 0.f};

    // 3 gld16 per wave per stage (vmcnt quantum = 3)
    auto stage = [&](int kt, char* base) {
        char* Xb_ = base;
        char* Wb_ = base + 8192;
        const char* sx_ = Xg + (size_t)(t0 + 8 * wid + l8) * 8192
                          + (size_t)kt * 128 + xu * 16;
        gld16(sx_, Xb_ + wid * 1024);
        #pragma unroll
        for (int q = 0; q < 2; ++q) {
            int i_ = wid * 2 + q;
            gld16(Wg + (size_t)kt * 16384 + i_ * 1024 + lane * 16, Wb_ + i_ * 1024);
        }
    };

    stage(0, smem);
    stage(1, smem + BUFB);
    asm volatile("s_waitcnt vmcnt(3)" ::: "memory");
    __builtin_amdgcn_s_barrier();

    int rd = 0, st = 2 * BUFB;
    for (int kt = 0; kt < NKT; ++kt) {
        const bool do_stage = (kt + 2 < NKT);
        if (do_stage) stage(kt + 2, smem + st);

        const char* Xb = smem + rd;
        const char* Wb = Xb + 8192;

        // A fragment (16 tokens) + hi/lo split
        bf16x8 ah, al;
        {
            int ar = wr * 16 + l15;
            int r7 = ar & 7;
            const char* rp = Xb + ar * 128;
            float4 fa = *(const float4*)(rp + (((2 * lhi) ^ r7) * 16));
            float4 fb = *(const float4*)(rp + (((2 * lhi + 1) ^ r7) * 16));
            float f[8] = {fa.x, fa.y, fa.z, fa.w, fb.x, fb.y, fb.z, fb.w};
            #pragma unroll
            for (int e = 0; e < 8; ++e) {
                unsigned short h = f2bf(f[e]);
                ah[e] = (short)h;
                float fh = __builtin_bit_cast(float, ((unsigned int)h) << 16);
                al[e] = (short)f2bf(f[e] - fh);
            }
        }
        // B fragments (64 experts), pre-split hi/lo from Wt
        bf16x8 bw[4][2];
        #pragma unroll
        for (int j = 0; j < 4; ++j) {
            int br = wc * 64 + j * 16 + l15;
            int r7 = br & 7;
            const char* rp = Wb + br * 128;
            bw[j][0] = *(const bf16x8*)(rp + ((lhi ^ r7) * 16));
            bw[j][1] = *(const bf16x8*)(rp + (((4 + lhi) ^ r7) * 16));
        }
        #pragma unroll
        for (int j = 0; j < 4; ++j) {
            acc[j] = __builtin_amdgcn_mfma_f32_16x16x32_bf16(ah, bw[j][0], acc[j], 0, 0, 0);
            acc[j] = __builtin_amdgcn_mfma_f32_16x16x32_bf16(al, bw[j][0], acc[j], 0, 0, 0);
            acc[j] = __builtin_amdgcn_mfma_f32_16x16x32_bf16(ah, bw[j][1], acc[j], 0, 0, 0);
        }

        if (do_stage) asm volatile("s_waitcnt vmcnt(3)" ::: "memory");
        else          asm volatile("s_waitcnt vmcnt(0)" ::: "memory");
        __builtin_amdgcn_s_barrier();

        rd = (rd == 2 * BUFB) ? 0 : rd + BUFB;
        st = (st == 2 * BUFB) ? 0 : st + BUFB;
    }

    // ---- logits -> LDS union (f32, stride 129) ----
    float* lg = (float*)smem;
    #pragma unroll
    for (int j = 0; j < 4; ++j)
        #pragma unroll
        for (int q = 0; q < 4; ++q) {
            int tr = wr * 16 + lhi * 4 + q;    // C/D: row=(lane>>4)*4+reg
            int ec = wc * 64 + j * 16 + l15;   //      col=lane&15
            lg[tr * 129 + ec] = acc[j][q];
        }

    // ---- cooperative zero of this block's dense score rows ----
    float* scoreBase = out + (size_t)t0 * NE;
    #pragma unroll
    for (int q = 0; q < 4; ++q) {
        int i = tid + q * 512;
        *(float4*)(scoreBase + (size_t)i * 4) = make_float4(0.f, 0.f, 0.f, 0.f);
    }
    __syncthreads();

    // ---- per-token epilogue: top-13 insert-sort, gap check, flag ----
    if (tid < BT) {
        const float* row = lg + tid * 129;
        float tv[13]; int ti[13];
        #pragma unroll
        for (int k = 0; k < 13; ++k) { tv[k] = -3.0e38f; ti[k] = 0; }
        for (int e = 0; e < NE; ++e) {
            float v = row[e];
            if (v > tv[12]) {
                float cv = v; int ci = e;
                #pragma unroll
                for (int s = 0; s < 13; ++s) {
                    if (cv > tv[s]) {
                        float t1 = tv[s]; int t2 = ti[s];
                        tv[s] = cv; ti[s] = ci; cv = t1; ci = t2;
                    }
                }
            }
        }
        bool flag = false;
        #pragma unroll
        for (int k = 0; k < 8; ++k) flag |= (tv[k] - tv[k + 1] < TWO_B);

        float pv[8]; float ksum = 0.f;
        #pragma unroll
        for (int k = 0; k < 8; ++k) { pv[k] = expf(tv[k] - tv[0]); ksum += pv[k]; }
        const int tg = t0 + tid;
        float* srow = out + (size_t)tg * NE;
        float* irow = out + (size_t)NT * NE + (size_t)tg * TOPK;
        #pragma unroll
        for (int k = 0; k < 8; ++k) {
            srow[ti[k]] = pv[k] / ksum;
            irow[k] = (float)ti[k];
        }

        if (flag) {
            unsigned int cnt;
            unsigned int idw[4] = {0u, 0u, 0u, 0u};
            float thr = tv[7] - TWO_B;
            if (tv[12] >= thr) {
                cnt = 0xFFu;
            } else {
                cnt = 0;
                #pragma unroll
                for (int k = 0; k < 13; ++k) {
                    if (k < 8 || tv[k] >= thr) {
                        idw[cnt >> 2] |= ((unsigned int)ti[k]) << ((cnt & 3) * 8);
                        ++cnt;
                    }
                }
            }
            unsigned int slot = atomicAdd(ws, 1u);
            unsigned int* rec = ws + WS_REC_U32 + slot * 8;
            rec[0] = (unsigned int)tg;
            rec[1] = cnt;
            rec[2] = idw[0]; rec[3] = idw[1]; rec[4] = idw[2]; rec[5] = idw[3];
        }
    }
}

// ---------------- K2: f64 refine flagged tokens ----------------
__global__ __launch_bounds__(256) void finalize_kernel(
    const float* __restrict__ X, const float* __restrict__ W,
    float* __restrict__ out, const unsigned int* __restrict__ ws)
{
    __shared__ float  xs[2048];
    __shared__ double cv[128];
    __shared__ int    cid[128];
    __shared__ float  ovals[8];
    __shared__ int    oidx[8];

    const int tid = threadIdx.x;
    const int lane = tid & 63, w = tid >> 6;
    const unsigned int n = ws[0];

    for (unsigned int rI = blockIdx.x; rI < n; rI += gridDim.x) {
        const unsigned int* rec = ws + WS_REC_U32 + rI * 8;
        const int tg = (int)rec[0];
        const unsigned int cnt = rec[1];
        const unsigned char* ids = (const unsigned char*)(rec + 2);
        const int nc = (cnt == 0xFFu) ? NE : (int)cnt;

        #pragma unroll
        for (int q = 0; q < 2; ++q) {
            int i = tid + q * 256;
            *(float4*)(xs + i * 4) = *(const float4*)(X + (size_t)tg * NH + i * 4);
        }
        __syncthreads();

        for (int c = w; c < nc; c += 4) {
            int e = (cnt == 0xFFu) ? c : (int)ids[c];
            const float* wrow = W + (size_t)e * NH;
            double s = 0.0;
            #pragma unroll
            for (int m = 0; m < 8; ++m) {
                float4 wv = *(const float4*)(wrow + m * 256 + lane * 4);
                float4 xv = *(const float4*)(xs + m * 256 + lane * 4);
                s = fma((double)xv.x, (double)wv.x, s);
                s = fma((double)xv.y, (double)wv.y, s);
                s = fma((double)xv.z, (double)wv.z, s);
                s = fma((double)xv.w, (double)wv.w, s);
            }
            #pragma unroll
            for (int off = 32; off >= 1; off >>= 1) s += __shfl_xor(s, off);
            if (lane == 0) { cv[c] = s; cid[c] = e; }
        }
        __syncthreads();

        if (tid == 0) {
            double lv[8];
            #pragma unroll
            for (int k = 0; k < 8; ++k) {
                double best = -1.0e300; int bi = 1 << 30, bc = 0;
                for (int c = 0; c < nc; ++c) {
                    double v = cv[c]; int e = cid[c];
                    if (v > best || (v == best && e < bi)) { best = v; bi = e; bc = c; }
                }
                lv[k] = best; oidx[k] = bi; cv[bc] = -1.0e301;
            }
            double m = lv[0], sum = 0.0, p[8];
            #pragma unroll
            for (int k = 0; k < 8; ++k) { p[k] = exp(lv[k] - m); sum += p[k]; }
            #pragma unroll
            for (int k = 0; k < 8; ++k) ovals[k] = (float)(p[k] / sum);
        }
        __syncthreads();

        float* srow = out + (size_t)tg * NE;
        if (tid < NE) {
            float val = 0.f;
            #pragma unroll
            for (int k = 0; k < 8; ++k) if (oidx[k] == tid) val = ovals[k];
            srow[tid] = val;
        }
        if (tid < TOPK) out[(size_t)NT * NE + (size_t)tg * TOPK + tid] = (float)oidx[tid];
        __syncthreads();
    }
}

extern "C" void kernel_launch(void* const* d_in, const int* in_sizes, int n_in,
                              void* d_out, int out_size, void* d_ws, size_t ws_size,
                              hipStream_t stream) {
    const float* X = (const float*)d_in[0];
    const float* W = (const float*)d_in[1];
    float* out = (float*)d_out;
    unsigned char* wsb = (unsigned char*)d_ws;
    unsigned short* Wt = (unsigned short*)(wsb + WS_W_OFF);

    hipMemsetAsync(d_ws, 0, 64, stream);
    prep_w_kernel<<<256, 256, 0, stream>>>(W, Wt);
    router_gemm_kernel<<<NT / BT, 512, 0, stream>>>(X, Wt, out, (unsigned int*)d_ws);
    finalize_kernel<<<1024, 256, 0, stream>>>(X, W, out, (const unsigned int*)d_ws);
}

// Round 6
// 196.824 us; speedup vs baseline: 2.5269x; 1.1702x over previous
//
#include <hip/hip_runtime.h>
#include <hip/hip_bf16.h>

#define NT   32768
#define NH   2048
#define NE   128
#define TOPK 8
#define BT   32
#define BND    6.0e-4f
#define TWO_B  (2.0f * BND)

// ws layout (bytes):
//   [0,64):          u32 flagged-token counter
//   [64, 64+1MB):    Wt2: B-fragment-ordered split-bf16 W.
//                    chunk g (512 u16 = 1KB), g = ((k32*2+s)*8+te)*1 ... :
//                    lane l holds Wsplit_s[te*16+(l&15)][k32*32+(l>>4)*8 ..+8)
//   [64+1MB, ...):   records, 32B each: u32 token, u32 cnt, 16x u8 cand ids
#define WS_W_OFF   64
#define WS_REC_U32 262160     // (64 + 1MB)/4

typedef __attribute__((ext_vector_type(8))) short bf16x8;
typedef __attribute__((ext_vector_type(4))) float f32x4;

static __device__ __forceinline__ unsigned short f2bf(float f) {
    __hip_bfloat16 h = __float2bfloat16(f);
    return *reinterpret_cast<unsigned short*>(&h);
}

// ---------------- K0: build B-fragment-ordered W hi/lo chunks ----------------
__global__ __launch_bounds__(256) void prep_w_kernel(
    const float* __restrict__ W, unsigned short* __restrict__ Wt)
{
    int g = blockIdx.x * 256 + threadIdx.x;   // 65536 16B-per-lane chunks
    int lane = g & 63;
    int te   = (g >> 6) & 7;
    int s    = (g >> 9) & 1;
    int k32  = g >> 10;
    int row  = te * 16 + (lane & 15);
    int kb   = k32 * 32 + (lane >> 4) * 8;
    const float* src = W + (size_t)row * NH + kb;
    float4 f0 = *(const float4*)src;
    float4 f1 = *(const float4*)(src + 4);
    float f[8] = {f0.x, f0.y, f0.z, f0.w, f1.x, f1.y, f1.z, f1.w};
    bf16x8 o;
    #pragma unroll
    for (int e = 0; e < 8; ++e) {
        unsigned short h = f2bf(f[e]);
        if (s == 0) o[e] = (short)h;
        else {
            float fh = __builtin_bit_cast(float, ((unsigned int)h) << 16);
            o[e] = (short)f2bf(f[e] - fh);
        }
    }
    *(bf16x8*)(Wt + (size_t)g * 8) = o;
}

// ---------------- K1: barrier-free reg-direct split-bf16 MFMA GEMM ----------------
// 256 thr = 4 waves; wave w owns K-slice [w*512, w*512+512); 32 tokens/block.
__global__ __launch_bounds__(256, 3) void router_gemm_kernel(
    const float* __restrict__ X, const unsigned short* __restrict__ Wt,
    float* __restrict__ out, unsigned int* __restrict__ ws)
{
    __shared__ float ps[2][BT * 132];   // 2 partial slices, stride 132 (33.8KB)

    const int tid  = threadIdx.x;
    const int lane = tid & 63;
    const int w    = tid >> 6;           // 0..3
    const int l15  = lane & 15, lhi = lane >> 4;
    const int t0   = blockIdx.x * BT;

    f32x4 acc[2][8];
    #pragma unroll
    for (int i = 0; i < 2; ++i)
        #pragma unroll
        for (int te = 0; te < 8; ++te) acc[i][te] = (f32x4){0.f, 0.f, 0.f, 0.f};

    const float* x0 = X + (size_t)(t0 + l15) * NH + lhi * 8;
    const float* x1 = X + (size_t)(t0 + 16 + l15) * NH + lhi * 8;
    const int kbase = w * 512;

    #pragma unroll 2
    for (int kk = 0; kk < 16; ++kk) {
        const int k = kbase + kk * 32;
        // A-fragments: 8 consecutive f32 per lane, split hi/lo
        bf16x8 ah[2], al[2];
        #pragma unroll
        for (int i = 0; i < 2; ++i) {
            const float* xp = (i ? x1 : x0) + k;
            float4 fa = *(const float4*)xp;
            float4 fb = *(const float4*)(xp + 4);
            float f[8] = {fa.x, fa.y, fa.z, fa.w, fb.x, fb.y, fb.z, fb.w};
            #pragma unroll
            for (int e = 0; e < 8; ++e) {
                unsigned short h = f2bf(f[e]);
                ah[i][e] = (short)h;
                float fh = __builtin_bit_cast(float, ((unsigned int)h) << 16);
                al[i][e] = (short)f2bf(f[e] - fh);
            }
        }
        // B-fragments: coalesced 1KB chunks from Wt2 (L2-resident)
        const unsigned short* wb = Wt + (size_t)(w * 16 + kk) * 8192;
        #pragma unroll
        for (int te = 0; te < 8; ++te) {
            bf16x8 bh = *(const bf16x8*)(wb + te * 512 + lane * 8);
            bf16x8 bl = *(const bf16x8*)(wb + 4096 + te * 512 + lane * 8);
            acc[0][te] = __builtin_amdgcn_mfma_f32_16x16x32_bf16(ah[0], bh, acc[0][te], 0, 0, 0);
            acc[1][te] = __builtin_amdgcn_mfma_f32_16x16x32_bf16(ah[1], bh, acc[1][te], 0, 0, 0);
            acc[0][te] = __builtin_amdgcn_mfma_f32_16x16x32_bf16(al[0], bh, acc[0][te], 0, 0, 0);
            acc[1][te] = __builtin_amdgcn_mfma_f32_16x16x32_bf16(al[1], bh, acc[1][te], 0, 0, 0);
            acc[0][te] = __builtin_amdgcn_mfma_f32_16x16x32_bf16(ah[0], bl, acc[0][te], 0, 0, 0);
            acc[1][te] = __builtin_amdgcn_mfma_f32_16x16x32_bf16(ah[1], bl, acc[1][te], 0, 0, 0);
        }
    }

    // ---- cross-wave K reduction: waves 0,1 write; waves 2,3 add; fold ----
    if (w < 2) {
        #pragma unroll
        for (int i = 0; i < 2; ++i)
            #pragma unroll
            for (int te = 0; te < 8; ++te)
                #pragma unroll
                for (int q = 0; q < 4; ++q)
                    ps[w][(i * 16 + lhi * 4 + q) * 132 + te * 16 + l15] = acc[i][te][q];
    }
    __syncthreads();
    if (w >= 2) {
        #pragma unroll
        for (int i = 0; i < 2; ++i)
            #pragma unroll
            for (int te = 0; te < 8; ++te)
                #pragma unroll
                for (int q = 0; q < 4; ++q) {
                    int o = (i * 16 + lhi * 4 + q) * 132 + te * 16 + l15;
                    ps[w - 2][o] += acc[i][te][q];
                }
    }
    __syncthreads();
    // fold slice1 into slice0 (rows 0..31, cols 0..127 as float4)
    #pragma unroll
    for (int q = 0; q < 4; ++q) {
        int idx = tid + q * 256;                 // 0..1023
        int row = idx >> 5, c4 = idx & 31;
        int o = row * 132 + c4 * 4;
        float4 a = *(float4*)&ps[0][o];
        float4 b = *(float4*)&ps[1][o];
        a.x += b.x; a.y += b.y; a.z += b.z; a.w += b.w;
        *(float4*)&ps[0][o] = a;
    }
    // zero this block's dense score rows (32x128 f32)
    float* scoreBase = out + (size_t)t0 * NE;
    #pragma unroll
    for (int q = 0; q < 4; ++q) {
        int i = tid + q * 256;
        *(float4*)(scoreBase + (size_t)i * 4) = make_float4(0.f, 0.f, 0.f, 0.f);
    }
    __syncthreads();

    // ---- per-token epilogue: top-13 insert-sort, gap check, flag ----
    if (tid < BT) {
        const float* row = &ps[0][tid * 132];
        float tv[13]; int ti[13];
        #pragma unroll
        for (int k = 0; k < 13; ++k) { tv[k] = -3.0e38f; ti[k] = 0; }
        for (int e = 0; e < NE; ++e) {
            float v = row[e];
            if (v > tv[12]) {
                float cv = v; int ci = e;
                #pragma unroll
                for (int s = 0; s < 13; ++s) {
                    if (cv > tv[s]) {
                        float t1 = tv[s]; int t2 = ti[s];
                        tv[s] = cv; ti[s] = ci; cv = t1; ci = t2;
                    }
                }
            }
        }
        bool flag = false;
        #pragma unroll
        for (int k = 0; k < 8; ++k) flag |= (tv[k] - tv[k + 1] < TWO_B);

        float pv[8]; float ksum = 0.f;
        #pragma unroll
        for (int k = 0; k < 8; ++k) { pv[k] = expf(tv[k] - tv[0]); ksum += pv[k]; }
        const int tg = t0 + tid;
        float* srow = out + (size_t)tg * NE;
        float* irow = out + (size_t)NT * NE + (size_t)tg * TOPK;
        #pragma unroll
        for (int k = 0; k < 8; ++k) {
            srow[ti[k]] = pv[k] / ksum;
            irow[k] = (float)ti[k];
        }

        if (flag) {
            unsigned int cnt;
            unsigned int idw[4] = {0u, 0u, 0u, 0u};
            float thr = tv[7] - TWO_B;
            if (tv[12] >= thr) {
                cnt = 0xFFu;
            } else {
                cnt = 0;
                #pragma unroll
                for (int k = 0; k < 13; ++k) {
                    if (k < 8 || tv[k] >= thr) {
                        idw[cnt >> 2] |= ((unsigned int)ti[k]) << ((cnt & 3) * 8);
                        ++cnt;
                    }
                }
            }
            unsigned int slot = atomicAdd(ws, 1u);
            unsigned int* rec = ws + WS_REC_U32 + slot * 8;
            rec[0] = (unsigned int)tg;
            rec[1] = cnt;
            rec[2] = idw[0]; rec[3] = idw[1]; rec[4] = idw[2]; rec[5] = idw[3];
        }
    }
}

// ---------------- K2: f64 refine flagged tokens ----------------
__global__ __launch_bounds__(256) void finalize_kernel(
    const float* __restrict__ X, const float* __restrict__ W,
    float* __restrict__ out, const unsigned int* __restrict__ ws)
{
    __shared__ float  xs[2048];
    __shared__ double cv[128];
    __shared__ int    cid[128];
    __shared__ float  ovals[8];
    __shared__ int    oidx[8];

    const int tid = threadIdx.x;
    const int lane = tid & 63, w = tid >> 6;
    const unsigned int n = ws[0];

    for (unsigned int rI = blockIdx.x; rI < n; rI += gridDim.x) {
        const unsigned int* rec = ws + WS_REC_U32 + rI * 8;
        const int tg = (int)rec[0];
        const unsigned int cnt = rec[1];
        const unsigned char* ids = (const unsigned char*)(rec + 2);
        const int nc = (cnt == 0xFFu) ? NE : (int)cnt;

        #pragma unroll
        for (int q = 0; q < 2; ++q) {
            int i = tid + q * 256;
            *(float4*)(xs + i * 4) = *(const float4*)(X + (size_t)tg * NH + i * 4);
        }
        __syncthreads();

        for (int c = w; c < nc; c += 4) {
            int e = (cnt == 0xFFu) ? c : (int)ids[c];
            const float* wrow = W + (size_t)e * NH;
            double s = 0.0;
            #pragma unroll
            for (int m = 0; m < 8; ++m) {
                float4 wv = *(const float4*)(wrow + m * 256 + lane * 4);
                float4 xv = *(const float4*)(xs + m * 256 + lane * 4);
                s = fma((double)xv.x, (double)wv.x, s);
                s = fma((double)xv.y, (double)wv.y, s);
                s = fma((double)xv.z, (double)wv.z, s);
                s = fma((double)xv.w, (double)wv.w, s);
            }
            #pragma unroll
            for (int off = 32; off >= 1; off >>= 1) s += __shfl_xor(s, off);
            if (lane == 0) { cv[c] = s; cid[c] = e; }
        }
        __syncthreads();

        if (tid == 0) {
            double lv[8];
            #pragma unroll
            for (int k = 0; k < 8; ++k) {
                double best = -1.0e300; int bi = 1 << 30, bc = 0;
                for (int c = 0; c < nc; ++c) {
                    double v = cv[c]; int e = cid[c];
                    if (v > best || (v == best && e < bi)) { best = v; bi = e; bc = c; }
                }
                lv[k] = best; oidx[k] = bi; cv[bc] = -1.0e301;
            }
            double m = lv[0], sum = 0.0, p[8];
            #pragma unroll
            for (int k = 0; k < 8; ++k) { p[k] = exp(lv[k] - m); sum += p[k]; }
            #pragma unroll
            for (int k = 0; k < 8; ++k) ovals[k] = (float)(p[k] / sum);
        }
        __syncthreads();

        float* srow = out + (size_t)tg * NE;
        if (tid < NE) {
            float val = 0.f;
            #pragma unroll
            for (int k = 0; k < 8; ++k) if (oidx[k] == tid) val = ovals[k];
            srow[tid] = val;
        }
        if (tid < TOPK) out[(size_t)NT * NE + (size_t)tg * TOPK + tid] = (float)oidx[tid];
        __syncthreads();
    }
}

extern "C" void kernel_launch(void* const* d_in, const int* in_sizes, int n_in,
                              void* d_out, int out_size, void* d_ws, size_t ws_size,
                              hipStream_t stream) {
    const float* X = (const float*)d_in[0];
    const float* W = (const float*)d_in[1];
    float* out = (float*)d_out;
    unsigned char* wsb = (unsigned char*)d_ws;
    unsigned short* Wt = (unsigned short*)(wsb + WS_W_OFF);

    hipMemsetAsync(d_ws, 0, 64, stream);
    prep_w_kernel<<<256, 256, 0, stream>>>(W, Wt);
    router_gemm_kernel<<<NT / BT, 256, 0, stream>>>(X, Wt, out, (unsigned int*)d_ws);
    finalize_kernel<<<1024, 256, 0, stream>>>(X, W, out, (const unsigned int*)d_ws);
}